// Round 14
// baseline (203.095 us; speedup 1.0000x reference)
//
#include <hip/hip_runtime.h>
#include <hip/hip_bf16.h>

// MetaConv2d two-pass, round 14.
// Kernel A (unchanged): hypernetwork -> W2 in B-fragment consumption order:
//   W2[node][q][cc2][k][l16][g] bf16  (12288 shorts / node)
// Kernel B (REWRITTEN): fully wave-independent streaming conv.
//   - 256-thread blocks, ZERO LDS, ZERO barriers. Wave owns (node, t-half).
//   - x A-fragments: direct global->reg, 24 independent float4 in 2 groups
//     (reg-peak capped); W B-fragments: two named sets, depth-1 rotation;
//     bias from precomputed biasT[8192][64] (new prepass, 2MB ws).
//   - Every wave an independent latency-hiding agent (no lockstep coupling).
// r13 post-mortem: 16-wave barrier'd blocks kept all pipes <7% at 35% occ;
// prefetch alone didn't fix it because the block structure was the coupler.

#define BN_TOT   8192
#define C_IN     64
#define C_OUT    64
#define M_DIM    32
#define S_OUT    62
#define WLW_ROWS 12288

#define NODE_W2  12288        // shorts per node in W2 (4q*3072)
#define A_STN    1544         // kernel A LDS node stride (8*192 + 8)

typedef __attribute__((ext_vector_type(8))) short bf16x8;
typedef __attribute__((ext_vector_type(4))) float f32x4;

static __device__ __forceinline__ short f2bf(float f) {
    return __bfloat16_as_short(__float2bfloat16(f));
}

static __device__ __forceinline__ bf16x8 cvt8(float4 a, float4 b) {
    bf16x8 r;
    r[0] = f2bf(a.x); r[1] = f2bf(a.y); r[2] = f2bf(a.z); r[3] = f2bf(a.w);
    r[4] = f2bf(b.x); r[5] = f2bf(b.y); r[6] = f2bf(b.z); r[7] = f2bf(b.w);
    return r;
}

// ---- pre-pass 1: w_lin_w f32 -> bf16, permuted to kernel A's load order ----
extern "C" __global__ void wlw_perm_bf16(const float* __restrict__ src,
                                         short* __restrict__ dst) {
    const int i = blockIdx.x * 256 + threadIdx.x;   // 49152 = 12288 rows x 4
    const int p = i >> 2;
    const int g = i & 3;
    const int o = p / 192;
    const int r = p - o * 192;
    const int c = r / 3;
    const int k = r - c * 3;
    const float4 a = *reinterpret_cast<const float4*>(src + p * 32 + g * 8);
    const float4 b = *reinterpret_cast<const float4*>(src + p * 32 + g * 8 + 4);
    const int off = o * 6144 + (c >> 4) * 1536 + k * 512 + (c & 15) * 32 + g * 8;
    *reinterpret_cast<bf16x8*>(dst + off) = cvt8(a, b);
}

// ---- pre-pass 2: wlb -> wlbR[o][k][c] f32 ----
extern "C" __global__ void wlb_rearr(const float* __restrict__ wlb,
                                     float* __restrict__ wlbR) {
    const int i = blockIdx.x * 256 + threadIdx.x;
    const int o = i / 192;
    const int r = i - o * 192;
    const int k = r >> 6;
    const int c = r & 63;
    wlbR[i] = wlb[o * 192 + c * 3 + k];
}

// ---- pre-pass 3: bias table biasT[bn][o] = meta[bn]·blw[o] + blb[o] ----
extern "C" __global__ void bias_all(const float* __restrict__ meta,
                                    const float* __restrict__ blw,
                                    const float* __restrict__ blb,
                                    float* __restrict__ biasT) {
    const int i  = blockIdx.x * 256 + threadIdx.x;  // 524288 = 8192*64
    const int bn = i >> 6;
    const int o  = i & 63;
    const float* mrow = meta + (size_t)bn * M_DIM;
    const float* brow = blw + o * M_DIM;
    float s = blb[o];
    #pragma unroll
    for (int m = 0; m < M_DIM; ++m) s += mrow[m] * brow[m];
    biasT[i] = s;
}

// ---------------- kernel A: hypernetwork -> W2 (unchanged from r12) --------
extern "C" __global__ void __launch_bounds__(512, 4)
hyper_write_w(const float* __restrict__ meta,    // [8192][32]
              const short* __restrict__ WP,      // permuted wlw bf16
              const float* __restrict__ wlbR,    // [64][3][64] f32
              short* __restrict__ W2,            // [nodes][12288] bf16
              int bn_base)
{
    __shared__ short st[16 * A_STN];             // [node][8 ow][192] (+8 pad)

    const int tid  = threadIdx.x;
    const int wave = tid >> 6;                   // ow 0..7
    const int lane = tid & 63;
    const int l16  = lane & 15;
    const int g    = lane >> 4;
    const int bn0  = bn_base + blockIdx.x * 16;
    const int og   = blockIdx.y * 8 + wave;

    bf16x8 metaF;                                // B-frag: 16 node columns
    {
        const float* mp = meta + (size_t)(bn0 + l16) * M_DIM + g * 8;
        metaF = cvt8(*reinterpret_cast<const float4*>(mp),
                     *reinterpret_cast<const float4*>(mp + 4));
    }

    #pragma unroll 1
    for (int cp = 0; cp < 2; ++cp) {
        #pragma unroll
        for (int ci = 0; ci < 2; ++ci) {
            const int ch4 = cp * 2 + ci;         // c-16-group 0..3
            #pragma unroll
            for (int k = 0; k < 3; ++k) {
                const bf16x8 aF = *reinterpret_cast<const bf16x8*>(
                    WP + og * 6144 + ch4 * 1536 + k * 512 + l16 * 32 + g * 8);
                const float4 cf = *reinterpret_cast<const float4*>(
                    wlbR + (og * 3 + k) * 64 + ch4 * 16 + g * 4);
                f32x4 Cf; Cf[0] = cf.x; Cf[1] = cf.y; Cf[2] = cf.z; Cf[3] = cf.w;
                const f32x4 d = __builtin_amdgcn_mfma_f32_16x16x32_bf16(aF, metaF, Cf, 0, 0, 0);
                *reinterpret_cast<short4*>(
                    &st[l16 * A_STN + wave * 192 + k * 64 + ch4 * 16 + g * 4]) =
                    make_short4(f2bf(d[0]), f2bf(d[1]), f2bf(d[2]), f2bf(d[3]));
            }
        }
    }
    __syncthreads();

    const int nb = blockIdx.x * 16;
    #pragma unroll
    for (int i = 0; i < 6; ++i) {
        const int u    = i * 512 + tid;
        const int node = u / 192;
        const int rem  = u - node * 192;
        const int ow   = rem / 24;
        const int rk   = rem - ow * 24;
        const int k    = rk >> 3;
        const int gb   = rk & 7;
        const int4 v = *reinterpret_cast<const int4*>(
            &st[node * A_STN + ow * 192 + k * 64 + gb * 8]);
        const int og2 = blockIdx.y * 8 + ow;
        *reinterpret_cast<int4*>(
            W2 + (size_t)(nb + node) * NODE_W2 + (og2 >> 4) * 3072 +
            (gb >> 2) * 1536 + k * 512 + (og2 & 15) * 32 + (gb & 3) * 8) = v;
    }
}

// ---------------- kernel B: wave-independent streaming conv ----------------
extern "C" __global__ void __launch_bounds__(256, 4)
conv_stream(const float* __restrict__ x,         // [8192][64][64]
            const short* __restrict__ W2,        // [nodes][12288] bf16 (ws)
            const float* __restrict__ biasT,     // [8192][64] f32 (ws)
            float* __restrict__ out,             // [8192][62][64]
            int bn_base)
{
    const int tid   = threadIdx.x;
    const int wave  = tid >> 6;                  // 0..3
    const int lane  = tid & 63;
    const int l16   = lane & 15;
    const int g     = lane >> 4;
    const int nodeL = blockIdx.x * 2 + (wave >> 1);   // chunk-local node
    const int thalf = wave & 1;
    const int bn    = bn_base + nodeL;

    const float* xb = x + (size_t)bn * (64 * C_IN);
    const short* Wn = W2 + (size_t)nodeL * NODE_W2;

    // bias for this lane's 4 o-values (issued first, used only at stores)
    float bias4[4];
    #pragma unroll
    for (int q = 0; q < 4; ++q)
        bias4[q] = biasT[(size_t)bn * 64 + q * 16 + l16];

    // ---- x A-fragments: direct global->reg, two groups of 12 float4 ----
    // A[ttl][i], i = cc2*3+k: lane holds x[t0+ttl*16+l16+k][cc2*32+g*8 ..+8]
    bf16x8 A0[6], A1[6];
    {
        float4 ra[6], rb[6];
        #pragma unroll
        for (int i = 0; i < 6; ++i) {            // ttl=0 (rows <= 49: no clamp)
            const int cc2 = i / 3, k = i - (i / 3) * 3;
            const int row = thalf * 32 + l16 + k;
            const float* p = xb + row * 64 + cc2 * 32 + g * 8;
            ra[i] = *reinterpret_cast<const float4*>(p);
            rb[i] = *reinterpret_cast<const float4*>(p + 4);
        }
        float4 rc[6], rd[6];
        #pragma unroll
        for (int i = 0; i < 6; ++i) {            // ttl=1 (clamp rows >= 63)
            const int cc2 = i / 3, k = i - (i / 3) * 3;
            int row = thalf * 32 + 16 + l16 + k;
            row = row < 63 ? row : 63;           // t>=62 outputs discarded
            const float* p = xb + row * 64 + cc2 * 32 + g * 8;
            rc[i] = *reinterpret_cast<const float4*>(p);
            rd[i] = *reinterpret_cast<const float4*>(p + 4);
        }
        #pragma unroll
        for (int i = 0; i < 6; ++i) A0[i] = cvt8(ra[i], rb[i]);   // frees ra/rb
        #pragma unroll
        for (int i = 0; i < 6; ++i) A1[i] = cvt8(rc[i], rd[i]);   // frees rc/rd
    }

    // ---- W B-fragments: two named sets, depth-1 rotation ----
    bf16x8 Bs0[6], Bs1[6];
    auto loadB = [&](int q, bf16x8 (&Bd)[6]) {
        #pragma unroll
        for (int cc2 = 0; cc2 < 2; ++cc2)
            #pragma unroll
            for (int k = 0; k < 3; ++k)
                Bd[cc2 * 3 + k] = *reinterpret_cast<const bf16x8*>(
                    Wn + q * 3072 + cc2 * 1536 + k * 512 + l16 * 32 + g * 8);
    };

    float* ob = out + (size_t)bn * (S_OUT * C_OUT);

    auto convq = [&](int q, bf16x8 (&Bc)[6], float bv) {
        const f32x4 ZV = {0.f, 0.f, 0.f, 0.f};
        f32x4 acc0 = ZV, acc1 = ZV;              // two independent MFMA chains
        #pragma unroll
        for (int i = 0; i < 6; ++i) {
            acc0 = __builtin_amdgcn_mfma_f32_16x16x32_bf16(A0[i], Bc[i], acc0, 0, 0, 0);
            acc1 = __builtin_amdgcn_mfma_f32_16x16x32_bf16(A1[i], Bc[i], acc1, 0, 0, 0);
        }
        const int o = q * 16 + l16;
        #pragma unroll
        for (int r = 0; r < 4; ++r) {
            const int t0 = thalf * 32 + g * 4 + r;
            ob[t0 * C_OUT + o] = acc0[r] + bv;               // t0 <= 47: in range
            const int t1 = t0 + 16;
            if (t1 < S_OUT) ob[t1 * C_OUT + o] = acc1[r] + bv;
        }
    };

    // ---- pipelined schedule (no barriers anywhere) ----
    loadB(0, Bs0);
    loadB(1, Bs1);
    convq(0, Bs0, bias4[0]);
    loadB(2, Bs0);
    convq(1, Bs1, bias4[1]);
    loadB(3, Bs1);
    convq(2, Bs0, bias4[2]);
    convq(3, Bs1, bias4[3]);
}

// ---------------- fallback: fused r6 kernel (no workspace) ----------------
#define OSTRF    104
#define WNODEF   (16 * OSTRF + 8)
#define WBUFF    (8 * WNODEF)

extern "C" __global__ void __launch_bounds__(1024, 4)
metaconv_fused_nows(const float* __restrict__ meta, const float* __restrict__ x,
                    const float* __restrict__ wlw, const float* __restrict__ wlb,
                    const float* __restrict__ blw, const float* __restrict__ blb,
                    float* __restrict__ out)
{
    __shared__ short wsh[2 * WBUFF];
    __shared__ short xshf[8 * 4096];
    __shared__ float bias_s[8][C_OUT];

    const int tid = threadIdx.x, wave = tid >> 6, lane = tid & 63;
    const int l16 = lane & 15, g = lane >> 4;
    const int node = wave & 7, thalf = wave >> 3;
    const int bn0 = blockIdx.x * 8;

    {
        const float* xsrc = x + (size_t)(bn0 + node) * (64 * C_IN);
        short* xd = xshf + node * 4096;
        const int ts0 = thalf * 32;
        #pragma unroll
        for (int i = 0; i < 4; ++i) {
            const int gi = i * 64 + lane;
            const int tl = ts0 + (gi >> 3), gr = gi & 7;
            const float4 a = *reinterpret_cast<const float4*>(xsrc + tl * 64 + gr * 8);
            const float4 b = *reinterpret_cast<const float4*>(xsrc + tl * 64 + gr * 8 + 4);
            const int so = (gr * 8) ^ ((tl & 7) << 3);
            *reinterpret_cast<bf16x8*>(xd + tl * 64 + so) = cvt8(a, b);
        }
    }
    if (tid < 8 * C_OUT) {
        const int bnode = tid >> 6, o = tid & 63;
        const float* mrow = meta + (size_t)(bn0 + bnode) * M_DIM;
        const float* brow = blw + o * M_DIM;
        float s = blb[o];
        #pragma unroll
        for (int m = 0; m < M_DIM; ++m) s += mrow[m] * brow[m];
        bias_s[bnode][o] = s;
    }
    bf16x8 metaF;
    {
        const float* mp = meta + (size_t)(bn0 + (l16 & 7)) * M_DIM + g * 8;
        metaF = cvt8(*reinterpret_cast<const float4*>(mp),
                     *reinterpret_cast<const float4*>(mp + 4));
    }
    auto hyper = [&](int c0, int oq, int buf) {
        const int og = oq * 16 + wave;
        short* wd = wsh + buf * WBUFF;
        #pragma unroll
        for (int ch = 0; ch < 2; ++ch) {
            #pragma unroll
            for (int k = 0; k < 3; ++k) {
                const int pr = og * 192 + (c0 + ch * 16 + l16) * 3 + k;
                const float* wp = wlw + (size_t)pr * M_DIM + g * 8;
                const bf16x8 aF = cvt8(*reinterpret_cast<const float4*>(wp),
                                       *reinterpret_cast<const float4*>(wp + 4));
                const int cb = c0 + ch * 16 + g * 4, pb = og * 192 + k;
                f32x4 Cf;
                Cf[0] = wlb[pb + (cb + 0) * 3]; Cf[1] = wlb[pb + (cb + 1) * 3];
                Cf[2] = wlb[pb + (cb + 2) * 3]; Cf[3] = wlb[pb + (cb + 3) * 3];
                const f32x4 d = __builtin_amdgcn_mfma_f32_16x16x32_bf16(aF, metaF, Cf, 0, 0, 0);
                if (l16 < 8) {
                    const int off = l16 * WNODEF + wave * OSTRF + k * 32 + ch * 16 + g * 4;
                    *reinterpret_cast<short4*>(&wd[off]) =
                        make_short4(f2bf(d[0]), f2bf(d[1]), f2bf(d[2]), f2bf(d[3]));
                }
            }
        }
    };
    const f32x4 ZV = {0.f, 0.f, 0.f, 0.f};
    f32x4 acc[2][4];
    #pragma unroll
    for (int t = 0; t < 2; ++t)
        #pragma unroll
        for (int o = 0; o < 4; ++o) acc[t][o] = ZV;

    hyper(0, 0, 0);
    __syncthreads();
    #pragma unroll
    for (int cc = 0; cc < 2; ++cc) {
        #pragma unroll
        for (int oq = 0; oq < 4; ++oq) {
            const int P = cc * 4 + oq;
            if (P < 7) hyper(((P + 1) >> 2) * 32, (P + 1) & 3, (P + 1) & 1);
            const short* wn = wsh + (P & 1) * WBUFF + node * WNODEF;
            const short* xn = xshf + node * 4096;
            bf16x8 B[3];
            #pragma unroll
            for (int k = 0; k < 3; ++k)
                B[k] = *reinterpret_cast<const bf16x8*>(wn + l16 * OSTRF + k * 32 + g * 8);
            #pragma unroll
            for (int ttl = 0; ttl < 2; ++ttl)
                #pragma unroll
                for (int k = 0; k < 3; ++k) {
                    int row = thalf * 32 + ttl * 16 + l16 + k;
                    row = row < 63 ? row : 63;
                    const int so = (cc * 32 + g * 8) ^ ((row & 7) << 3);
                    const bf16x8 A = *reinterpret_cast<const bf16x8*>(xn + row * 64 + so);
                    acc[ttl][oq] = __builtin_amdgcn_mfma_f32_16x16x32_bf16(
                        A, B[k], acc[ttl][oq], 0, 0, 0);
                }
            __syncthreads();
        }
    }
    float* ob = out + (size_t)(bn0 + node) * (S_OUT * C_OUT);
    #pragma unroll
    for (int ttl = 0; ttl < 2; ++ttl)
        #pragma unroll
        for (int ot = 0; ot < 4; ++ot) {
            const int o = ot * 16 + l16;
            const float bv = bias_s[node][o];
            #pragma unroll
            for (int r = 0; r < 4; ++r) {
                const int t = thalf * 32 + ttl * 16 + g * 4 + r;
                if (t < S_OUT) ob[t * C_OUT + o] = acc[ttl][ot][r] + bv;
            }
        }
}

// ---------------- launcher ----------------
extern "C" void kernel_launch(void* const* d_in, const int* in_sizes, int n_in,
                              void* d_out, int out_size, void* d_ws, size_t ws_size,
                              hipStream_t stream) {
    const float* meta = (const float*)d_in[0];
    const float* x    = (const float*)d_in[1];
    const float* wlw  = (const float*)d_in[2];
    const float* wlb  = (const float*)d_in[3];
    const float* blw  = (const float*)d_in[4];
    const float* blb  = (const float*)d_in[5];
    float* out = (float*)d_out;
    (void)in_sizes; (void)n_in; (void)out_size;

    // ws layout: WP 786432 | wlbR 49152 | biasT 2097152 | W2 chunk
    const size_t OFF_WLBR = 786432;
    const size_t OFF_BIAS = 835584;
    const size_t OFF_W2   = 2932736;
    int nchunk = 0;
    for (int n = 1; n <= 8; n *= 2) {
        if (ws_size >= OFF_W2 + (size_t)(BN_TOT / n) * NODE_W2 * 2) { nchunk = n; break; }
    }

    if (nchunk) {
        short* WP    = (short*)d_ws;
        float* wlbR  = (float*)((char*)d_ws + OFF_WLBR);
        float* biasT = (float*)((char*)d_ws + OFF_BIAS);
        short* W2    = (short*)((char*)d_ws + OFF_W2);
        wlw_perm_bf16<<<dim3(192), dim3(256), 0, stream>>>(wlw, WP);
        wlb_rearr<<<dim3(WLW_ROWS / 256), dim3(256), 0, stream>>>(wlb, wlbR);
        bias_all<<<dim3(BN_TOT * 64 / 256), dim3(256), 0, stream>>>(meta, blw, blb, biasT);
        const int nodes = BN_TOT / nchunk;
        for (int c = 0; c < nchunk; ++c) {
            hyper_write_w<<<dim3(nodes / 16, 8), dim3(512), 0, stream>>>(
                meta, WP, wlbR, W2, c * nodes);
            conv_stream<<<dim3(nodes / 2), dim3(256), 0, stream>>>(
                x, W2, biasT, out, c * nodes);
        }
    } else {
        metaconv_fused_nows<<<dim3(BN_TOT / 8), dim3(1024), 0, stream>>>(
            meta, x, wlw, wlb, blw, blb, out);
    }
}

// Round 15
// 140.173 us; speedup vs baseline: 1.4489x; 1.4489x over previous
//
#include <hip/hip_runtime.h>
#include <hip/hip_bf16.h>

// MetaConv2d fused hypernetwork + dynamic conv, bf16 MFMA. FINAL (= round 6,
// the session's measured-best at 143.2 us wall).
// out[bn,t,o] = sum_{c,k} x[bn,t+k,c] * w[bn,o,c,k] + bias[bn,o]
//   w[bn,p]   = meta[bn,:]·w_lin_w[p,:] + w_lin_b[p],  p = o*192 + c*3 + k
//
// Block = 8 nodes, 1024 threads (16 waves = 8 nodes x 2 t-halves), grid 1024.
//  - x slab staged once into LDS as bf16 with a deep load queue (8 independent
//    float4 loads/lane) -> HBM latency covered at block start.
//  - xsh XOR-swizzled (idx ^= (row&7)<<3, write AND read) -> A-reads 2-way.
//  - all acc indices compile-time (runtime-indexed acc goes to scratch).
// Phases (4 = 2 c-chunks x 2 o-halves):
//   { hyper (12 tiles/wave, 2 groups of 6) -> w_lds; barrier;
//     conv (6 B + 6 A ds_reads, 12 MFMA into persistent acc); barrier; }
// LDS: dynamic 119 KB = x 64 KB + w 53.4 KB; static 2 KB bias.
//
// Session post-mortems (r7-r14): pipelining/occupancy/TLP/two-pass streaming
// all land 143-219 us; the conv consumption alone floors at ~132 us in every
// structure tried, so the fused form (hyper effectively free under it) wins.

#define BN_TOT   8192
#define C_IN     64
#define C_OUT    64
#define M_DIM    32
#define S_OUT    62

#define NT       8            // nodes per block
#define NTHREADS 1024         // 16 waves
#define OSTR     104          // shorts per o-row in w_lds: 96 j + 8 pad (13 dwords: odd -> conflict-free)
#define NODESTR  3336         // 32*OSTR + 8
#define WLDSN    (NT * NODESTR)      // 26688 shorts
#define XLDSN    (NT * 64 * 64)      // 32768 shorts (x bf16, [node][t][c] swizzled)
#define DYNB     ((XLDSN + WLDSN) * 2)   // 118912 B
#define WLW_ROWS 12288
#define WS_NEED  (WLW_ROWS * M_DIM * 2 + WLW_ROWS * 4)

typedef __attribute__((ext_vector_type(8))) short bf16x8;
typedef __attribute__((ext_vector_type(4))) float f32x4;

static __device__ __forceinline__ short f2bf(float f) {
    return __bfloat16_as_short(__float2bfloat16(f));
}

static __device__ __forceinline__ bf16x8 cvt8(float4 a, float4 b) {
    bf16x8 r;
    r[0] = f2bf(a.x); r[1] = f2bf(a.y); r[2] = f2bf(a.z); r[3] = f2bf(a.w);
    r[4] = f2bf(b.x); r[5] = f2bf(b.y); r[6] = f2bf(b.z); r[7] = f2bf(b.w);
    return r;
}

// ---------------- pre-pass 1: w_lin_w f32 -> bf16 ----------------
extern "C" __global__ void wlw_to_bf16(const float* __restrict__ src,
                                       short* __restrict__ dst) {
    const int i = (blockIdx.x * 256 + threadIdx.x) * 8;
    const float4 a = *reinterpret_cast<const float4*>(src + i);
    const float4 b = *reinterpret_cast<const float4*>(src + i + 4);
    *reinterpret_cast<bf16x8*>(dst + i) = cvt8(a, b);
}

// ---------------- pre-pass 2: wlb -> wlbR[o][k][c] f32 ----------------
extern "C" __global__ void wlb_rearr(const float* __restrict__ wlb,
                                     float* __restrict__ wlbR) {
    const int i = blockIdx.x * 256 + threadIdx.x;
    const int o = i / 192;
    const int r = i - o * 192;
    const int k = r >> 6;
    const int c = r & 63;
    wlbR[i] = wlb[o * 192 + c * 3 + k];
}

// ---------------- fused kernel ----------------
template <int USE_WS>
__global__ void __launch_bounds__(NTHREADS, 4)
metaconv_fused(const float* __restrict__ meta,   // [8192][32]
               const float* __restrict__ x,      // [8192][64][64]
               const float* __restrict__ wlw,    // [12288][32] f32
               const short* __restrict__ wlwbf,  // [12288][32] bf16 (ws)
               const float* __restrict__ wlb,    // [12288]
               const float* __restrict__ wlbR,   // [64][3][64] (ws)
               const float* __restrict__ blw,    // [64][32]
               const float* __restrict__ blb,    // [64]
               float* __restrict__ out)          // [8192][62][64]
{
    extern __shared__ __align__(16) short dynsm[];
    short* xsh = dynsm;                  // [8][64][64] bf16, row-swizzled
    short* wsh = dynsm + XLDSN;          // [8][NODESTR]
    __shared__ float bias_s[NT][C_OUT];

    const int tid   = threadIdx.x;
    const int wave  = tid >> 6;          // 0..15
    const int lane  = tid & 63;
    const int l16   = lane & 15;
    const int g     = lane >> 4;
    const int node  = wave & (NT - 1);
    const int thalf = wave >> 3;
    const int bn0   = blockIdx.x * NT;

    // ---- stage x slab: 8 independent float4 loads/lane (deep HBM queue) ----
    // xsh layout: node*4096 + t*64 + (granule*8 ^ ((t&7)<<3))   [shorts]
    {
        const float* xsrc = x + (size_t)(bn0 + node) * (64 * C_IN);
        short* xdst = xsh + node * 4096;
        const int ts0 = thalf * 32;
        #pragma unroll
        for (int i = 0; i < 4; ++i) {
            const int gi = i * 64 + lane;          // 0..255 granules (32 t x 8)
            const int tl = ts0 + (gi >> 3);
            const int gr = gi & 7;
            const float4 a = *reinterpret_cast<const float4*>(xsrc + tl * 64 + gr * 8);
            const float4 b = *reinterpret_cast<const float4*>(xsrc + tl * 64 + gr * 8 + 4);
            const int so = (gr * 8) ^ ((tl & 7) << 3);
            *reinterpret_cast<bf16x8*>(xdst + tl * 64 + so) = cvt8(a, b);
        }
    }

    // per-block bias table (tid < 512)
    if (tid < NT * C_OUT) {
        const int bnode = tid >> 6;
        const int o     = tid & 63;
        const float* mrow = meta + (size_t)(bn0 + bnode) * M_DIM;
        const float* brow = blw + o * M_DIM;
        float s = blb[o];
        #pragma unroll
        for (int m = 0; m < M_DIM; ++m) s += mrow[m] * brow[m];
        bias_s[bnode][o] = s;
    }

    // meta B-fragment (cols = nodes; cols 8..15 duplicate, discarded on write)
    bf16x8 metaF;
    {
        const float* mp = meta + (size_t)(bn0 + (l16 & (NT - 1))) * M_DIM + g * 8;
        metaF = cvt8(*reinterpret_cast<const float4*>(mp),
                     *reinterpret_cast<const float4*>(mp + 4));
    }

    const f32x4 ZV = {0.f, 0.f, 0.f, 0.f};
    f32x4 acc[2][4];                     // [t-tile local][o-tile 0..3] — static idx only
    #pragma unroll
    for (int t = 0; t < 2; ++t)
        #pragma unroll
        for (int o = 0; o < 4; ++o) acc[t][o] = ZV;

    __syncthreads();                     // x staged, bias ready

    #pragma unroll 1
    for (int cchunk = 0; cchunk < 2; ++cchunk) {
        const int c0 = cchunk * 32;
        #pragma unroll
        for (int oh = 0; oh < 2; ++oh) {   // compile-time: acc index static

            // ---- hyper: 12 tiles/wave = 2 groups of 6 ----
            #pragma unroll 1
            for (int ou = 0; ou < 2; ++ou) {
                const int o_l = wave * 2 + ou;       // 0..31 within half
                const int og  = oh * 32 + o_l;       // global o
                #pragma unroll
                for (int ch = 0; ch < 2; ++ch) {
                    #pragma unroll
                    for (int k = 0; k < 3; ++k) {
                        const int pr = og * 192 + (c0 + ch * 16 + l16) * 3 + k;
                        bf16x8 aF;
                        f32x4 Cf;
                        if constexpr (USE_WS) {
                            aF = *reinterpret_cast<const bf16x8*>(wlwbf + (size_t)pr * M_DIM + g * 8);
                            const float4 cf = *reinterpret_cast<const float4*>(
                                wlbR + (og * 3 + k) * 64 + c0 + ch * 16 + g * 4);
                            Cf[0] = cf.x; Cf[1] = cf.y; Cf[2] = cf.z; Cf[3] = cf.w;
                        } else {
                            const float* wp = wlw + (size_t)pr * M_DIM + g * 8;
                            aF = cvt8(*reinterpret_cast<const float4*>(wp),
                                      *reinterpret_cast<const float4*>(wp + 4));
                            const int cb = c0 + ch * 16 + g * 4;
                            const int pb = og * 192 + k;
                            Cf[0] = wlb[pb + (cb + 0) * 3];
                            Cf[1] = wlb[pb + (cb + 1) * 3];
                            Cf[2] = wlb[pb + (cb + 2) * 3];
                            Cf[3] = wlb[pb + (cb + 3) * 3];
                        }
                        const f32x4 d = __builtin_amdgcn_mfma_f32_16x16x32_bf16(aF, metaF, Cf, 0, 0, 0);
                        if (l16 < NT) {
                            const int off = l16 * NODESTR + o_l * OSTR + k * 32 + ch * 16 + g * 4;
                            *reinterpret_cast<short4*>(&wsh[off]) =
                                make_short4(f2bf(d[0]), f2bf(d[1]), f2bf(d[2]), f2bf(d[3]));
                        }
                    }
                }
            }
            __syncthreads();             // w ready for conv

            // ---- conv: B-frags (LDS), A-frags (swizzled LDS), 12 MFMA ----
            const short* wn = wsh + node * NODESTR;
            const short* xn = xsh + node * 4096;
            bf16x8 B[3];
            #pragma unroll
            for (int k = 0; k < 3; ++k)
                B[k] = *reinterpret_cast<const bf16x8*>(
                    wn + l16 * OSTR + k * 32 + g * 8);

            #pragma unroll
            for (int ttl = 0; ttl < 2; ++ttl) {
                #pragma unroll
                for (int k = 0; k < 3; ++k) {
                    int row = thalf * 32 + ttl * 16 + l16 + k;
                    row = row < 63 ? row : 63;         // rows t>=62 discarded
                    const int so = (c0 + g * 8) ^ ((row & 7) << 3);
                    const bf16x8 A = *reinterpret_cast<const bf16x8*>(
                        xn + row * 64 + so);
                    acc[ttl][oh * 2 + 0] = __builtin_amdgcn_mfma_f32_16x16x32_bf16(
                        A, B[k], acc[ttl][oh * 2 + 0], 0, 0, 0);
                }
            }
            // second o-tile of this half (o_l 16..31): B-frags from offset 16
            bf16x8 B2[3];
            #pragma unroll
            for (int k = 0; k < 3; ++k)
                B2[k] = *reinterpret_cast<const bf16x8*>(
                    wn + (16 + l16) * OSTR + k * 32 + g * 8);
            #pragma unroll
            for (int ttl = 0; ttl < 2; ++ttl) {
                #pragma unroll
                for (int k = 0; k < 3; ++k) {
                    int row = thalf * 32 + ttl * 16 + l16 + k;
                    row = row < 63 ? row : 63;
                    const int so = (c0 + g * 8) ^ ((row & 7) << 3);
                    const bf16x8 A = *reinterpret_cast<const bf16x8*>(
                        xn + row * 64 + so);
                    acc[ttl][oh * 2 + 1] = __builtin_amdgcn_mfma_f32_16x16x32_bf16(
                        A, B2[k], acc[ttl][oh * 2 + 1], 0, 0, 0);
                }
            }
            __syncthreads();             // conv done before next hyper overwrite
        }
    }

    // ---------------- epilogue: add bias, store f32 ----------------
    float* ob = out + (size_t)(bn0 + node) * (S_OUT * C_OUT);
    #pragma unroll
    for (int ttl = 0; ttl < 2; ++ttl) {
        #pragma unroll
        for (int ot = 0; ot < 4; ++ot) {
            const int o  = ot * 16 + l16;
            const float bv = bias_s[node][o];
            #pragma unroll
            for (int r = 0; r < 4; ++r) {
                const int t = thalf * 32 + ttl * 16 + g * 4 + r;
                if (t < S_OUT) ob[t * C_OUT + o] = acc[ttl][ot][r] + bv;
            }
        }
    }
}

extern "C" void kernel_launch(void* const* d_in, const int* in_sizes, int n_in,
                              void* d_out, int out_size, void* d_ws, size_t ws_size,
                              hipStream_t stream) {
    const float* meta = (const float*)d_in[0];
    const float* x    = (const float*)d_in[1];
    const float* wlw  = (const float*)d_in[2];
    const float* wlb  = (const float*)d_in[3];
    const float* blw  = (const float*)d_in[4];
    const float* blb  = (const float*)d_in[5];
    float* out = (float*)d_out;
    (void)in_sizes; (void)n_in; (void)out_size;

    short* wlwbf = (short*)d_ws;
    float* wlbR  = (float*)((char*)d_ws + (size_t)WLW_ROWS * M_DIM * 2);

    if (ws_size >= (size_t)WS_NEED) {
        (void)hipFuncSetAttribute((const void*)&metaconv_fused<1>,
                                  hipFuncAttributeMaxDynamicSharedMemorySize, DYNB);
        wlw_to_bf16<<<dim3(WLW_ROWS * M_DIM / (256 * 8)), dim3(256), 0, stream>>>(wlw, wlwbf);
        wlb_rearr<<<dim3(WLW_ROWS / 256), dim3(256), 0, stream>>>(wlb, wlbR);
        metaconv_fused<1><<<dim3(BN_TOT / NT), dim3(NTHREADS), DYNB, stream>>>(
            meta, x, wlw, wlwbf, wlb, wlbR, blw, blb, out);
    } else {
        (void)hipFuncSetAttribute((const void*)&metaconv_fused<0>,
                                  hipFuncAttributeMaxDynamicSharedMemorySize, DYNB);
        metaconv_fused<0><<<dim3(BN_TOT / NT), dim3(NTHREADS), DYNB, stream>>>(
            meta, x, wlw, wlwbf, wlb, wlbR, blw, blb, out);
    }
}